// Round 11
// baseline (339.837 us; speedup 1.0000x reference)
//
#include <hip/hip_runtime.h>
#include <cstdint>

// B=4, T=4096, D=1024, H=16, d=64, C=64, N=T/C=64
#define B_ 4
#define T_ 4096
#define D_ 1024
#define H_ 16
#define HD_ 64
#define N_ 64

typedef __attribute__((ext_vector_type(8))) short s16x8;
typedef __attribute__((ext_vector_type(4))) float f32x4;

__device__ __forceinline__ unsigned short f2bf(float f) {
    unsigned int u = __builtin_bit_cast(unsigned int, f);
    u += 0x7fffu + ((u >> 16) & 1u);          // RNE
    return (unsigned short)(u >> 16);
}
__device__ __forceinline__ float bf2f(unsigned short h) {
    unsigned int u = ((unsigned int)h) << 16;
    return __builtin_bit_cast(float, u);
}
__device__ __forceinline__ void gl2lds(const short* g, short* l) {
    __builtin_amdgcn_global_load_lds(
        (const __attribute__((address_space(1))) void*)g,
        (__attribute__((address_space(3))) void*)l, 16, 0, 0);
}
#define MFMA16(a, b, c) __builtin_amdgcn_mfma_f32_16x16x32_bf16(a, b, c, 0, 0, 0)
#define SB0() __builtin_amdgcn_sched_barrier(0)
#define BAR() __builtin_amdgcn_s_barrier()

#define BF_P1 ((short)0x3F80)
#define BF_M1 ((short)0xBF80)

// ---------------------------------------------------------------------------
// Converters.
// ---------------------------------------------------------------------------
__global__ __launch_bounds__(256)
void k_cvt_split(const float* __restrict__ in, short* __restrict__ out,
                 short* __restrict__ out_hi, int n4)
{
    int i = blockIdx.x * blockDim.x + threadIdx.x;
    const int stride = gridDim.x * blockDim.x;
    for (; i < n4; i += stride) {
        float4 f = ((const float4*)in)[i];
        const float v[4] = {f.x, f.y, f.z, f.w};
        s16x8 o;
        short4 hi4;
        #pragma unroll
        for (int j = 0; j < 4; ++j) {
            unsigned short h = f2bf(v[j]);
            o[j*2]   = (short)h;
            o[j*2+1] = (short)f2bf(v[j] - bf2f(h));
            ((short*)&hi4)[j] = (short)h;
        }
        ((s16x8*)out)[i] = o;
        if (out_hi) *(short4*)(out_hi + i * 4) = hi4;
    }
}
__global__ __launch_bounds__(256)
void k_cvt(const float* __restrict__ in, short* __restrict__ out, int n4)
{
    int i = blockIdx.x * blockDim.x + threadIdx.x;
    const int stride = gridDim.x * blockDim.x;
    for (; i < n4; i += stride) {
        float4 f = ((const float4*)in)[i];
        short4 o;
        o.x = (short)f2bf(f.x); o.y = (short)f2bf(f.y);
        o.z = (short)f2bf(f.z); o.w = (short)f2bf(f.w);
        *(short4*)(out + i * 4) = o;
    }
}

// ---------------------------------------------------------------------------
// bf16 MFMA GEMM with 1-phase register READ-AHEAD: O = A @ B^T.
// 256x256 tile, BK=64, 512 thr (8 waves 2x4), 16x16x32 MFMA.
// Each phase: [stage half][counted vmcnt][ds_reads for quad q+1][SB0]
// [16 MFMA on quad q's fragments, read LAST phase][BAR].  MFMAs need no
// lgkm wait (operands settled); this phase's reads execute on the LDS pipe
// WHILE the matrix pipe runs the burst -> pipes overlap instead of
// serializing.  Fragments double-buffered in named regs (faA/faB/fbA/fbB).
// vmcnt(2) at ph0/ph2 retires exactly kh1(t) / kh0(t+1) (6 outstanding->2);
// consumers read only after the following barrier.  One barrier per phase.
// MODE 0: k/v epilogue (sign INT8 -> Kb8 [c][d] / VbT8 [d][c]).
// MODE 1: fp32 Y.  MODE 2: Q epilogue (bf16, *0.125).
// ---------------------------------------------------------------------------
template<int MODE, int KD, int NCB>
__global__ __launch_bounds__(512, 2)
void k_gemm(const short* __restrict__ A, const short* __restrict__ Bm,
            short* __restrict__ Oq, signed char* __restrict__ K8,
            signed char* __restrict__ V8, float* __restrict__ Yf)
{
    __shared__ __align__(16) short LS[2][2][2][8192];  // [dbuf][mat][kk][256*32]

    const int tid = threadIdx.x;
    const int nwg = 64 * NCB;
    const int bid = blockIdx.x;
    const int sz  = (bid & 7) * (nwg >> 3) + (bid >> 3);   // XCD-contiguous
    const int cb  = sz % NCB, rb = sz / NCB;
    const int row0 = rb * 256, col0 = cb * 256;

    const int lane = tid & 63, w = tid >> 6;
    const int wr = w >> 2, wc = w & 3;
    const int cl = lane & 15, rg = lane >> 4;

    const int srow  = lane >> 2;
    const int sslot = (lane & 3) ^ ((lane >> 3) & 3);
    const short* gA = A  + (size_t)(row0 + w * 32 + srow) * KD + sslot * 8;
    const short* gB = Bm + (size_t)(col0 + w * 32 + srow) * KD + sslot * 8;

    f32x4 acc[8][4];
    #pragma unroll
    for (int i = 0; i < 8; ++i)
        #pragma unroll
        for (int j = 0; j < 4; ++j) acc[i][j] = (f32x4)0.f;

    auto stageH = [&](int mat, int kk, int u) {
        const short* g = mat ? gB : gA;
        const int off = u * 64 + kk * 32;
        short* dst = &LS[u & 1][mat][kk][(w * 32) * 32];
        gl2lds(g + off, dst);
        gl2lds(g + 16 * KD + off, dst + 16 * 32);
    };
    auto ldf = [&](int pb, int mat, int kk, int R) -> s16x8 {
        const char* base = (const char*)&LS[pb][mat][kk][0];
        return *(const s16x8*)(base + R * 64 + ((rg ^ ((R >> 1) & 3)) << 4));
    };

    s16x8 faA[4], faB[4], fbA[4], fbB[4];
    auto rdAq = [&](s16x8* dst, int pb, int kk, int mh) {
        #pragma unroll
        for (int mi = 0; mi < 4; ++mi)
            dst[mi] = ldf(pb, 0, kk, wr * 128 + mh * 64 + mi * 16 + cl);
    };
    auto rdBq = [&](s16x8* dst, int pb, int kk) {
        #pragma unroll
        for (int ni = 0; ni < 4; ++ni)
            dst[ni] = ldf(pb, 1, kk, wc * 64 + ni * 16 + cl);
    };
    auto quad = [&](const s16x8* fa, const s16x8* fb, int mh) {
        __builtin_amdgcn_s_setprio(1);
        #pragma unroll
        for (int ni = 0; ni < 4; ++ni)
            #pragma unroll
            for (int mi = 0; mi < 4; ++mi)
                acc[mh * 4 + mi][ni] =
                    MFMA16(fa[mi], fb[ni], acc[mh * 4 + mi][ni]);
        __builtin_amdgcn_s_setprio(0);
    };

    const int nt = KD / 64;
    // prologue: tile 0 fully staged; retire kh0(0); preload quad-0 frags.
    stageH(0, 0, 0); stageH(1, 0, 0); stageH(0, 1, 0); stageH(1, 1, 0);
    asm volatile("s_waitcnt vmcnt(4)" ::: "memory");
    BAR();
    rdBq(fbA, 0, 0); rdAq(faA, 0, 0, 0);

    for (int t = 0; t < nt; ++t) {
        const int pb = t & 1;
        const bool st = (t + 1 < nt);
        // ---- ph0: stage A-kh0(t+1); retire kh1(t); read q1; MFMA q0 ----
        if (st) stageH(0, 0, t + 1);
        if (st) asm volatile("s_waitcnt vmcnt(2)" ::: "memory");
        else    asm volatile("s_waitcnt vmcnt(0)" ::: "memory");
        rdAq(faB, pb, 0, 1);
        SB0();
        quad(faA, fbA, 0);
        SB0(); BAR();
        // ---- ph1: stage B-kh0(t+1); read q2 (kk1); MFMA q1 ----
        if (st) stageH(1, 0, t + 1);
        rdBq(fbB, pb, 1); rdAq(faA, pb, 1, 0);
        SB0();
        quad(faB, fbA, 1);
        SB0(); BAR();
        // ---- ph2: stage A-kh1(t+1); retire kh0(t+1); read q3; MFMA q2 ----
        if (st) stageH(0, 1, t + 1);
        if (st) asm volatile("s_waitcnt vmcnt(2)" ::: "memory");
        rdAq(faB, pb, 1, 1);
        SB0();
        quad(faA, fbB, 0);
        SB0(); BAR();
        // ---- ph3: stage B-kh1(t+1); read q0(t+1) from buf pb^1; MFMA q3 ----
        if (st) stageH(1, 1, t + 1);
        if (st) { rdBq(fbA, pb ^ 1, 0); rdAq(faA, pb ^ 1, 0, 0); }
        SB0();
        quad(faB, fbB, 1);
        SB0(); BAR();
    }

    const int m0 = row0 + wr * 128, n0 = col0 + wc * 64;
    if (MODE == 0) {
        const int s = 1 + (col0 >> 10);       // 1:k 2:v, uniform per block
        #pragma unroll
        for (int ni = 0; ni < 4; ++ni) {
            const int col = n0 + ni * 16 + cl;
            const int h = (col & 1023) >> 6, dd = col & 63;
            #pragma unroll
            for (int mi = 0; mi < 8; ++mi)
                #pragma unroll
                for (int r = 0; r < 4; ++r) {
                    const int bt = m0 + mi * 16 + rg * 4 + r;
                    const int bb = bt >> 12, t = bt & (T_ - 1);
                    const size_t bh64 = (size_t)(bb * H_ + h);
                    const signed char sg = (acc[mi][ni][r] >= 0.f) ? 1 : -1;
                    if (s == 1) {
                        K8[(bh64 * T_ + t) * 64 + dd] = sg;   // Kb8 [c][d]
                    } else {
                        const size_t otr = bh64 * ((size_t)T_ * 64)
                                         + (size_t)(t >> 6) * 4096 + dd * 64 + (t & 63);
                        V8[otr] = sg;                         // VbT8 [d][c]
                    }
                }
        }
    } else if (MODE == 2) {
        #pragma unroll
        for (int ni = 0; ni < 4; ++ni) {
            const int col = n0 + ni * 16 + cl;
            const int h = col >> 6, dd = col & 63;
            #pragma unroll
            for (int mi = 0; mi < 8; ++mi)
                #pragma unroll
                for (int r = 0; r < 4; ++r) {
                    const int bt = m0 + mi * 16 + rg * 4 + r;
                    const int bb = bt >> 12, t = bt & (T_ - 1);
                    Oq[((size_t)(bb * H_ + h) * T_ + t) * 64 + dd] =
                        (short)f2bf(acc[mi][ni][r] * 0.125f);
                }
        }
    } else {
        #pragma unroll
        for (int ni = 0; ni < 4; ++ni) {
            const int col = n0 + ni * 16 + cl;
            #pragma unroll
            for (int mi = 0; mi < 8; ++mi)
                #pragma unroll
                for (int r = 0; r < 4; ++r)
                    Yf[(size_t)(m0 + mi * 16 + rg * 4 + r) * D_ + col] =
                        acc[mi][ni][r];
        }
    }
}

// ---------------------------------------------------------------------------
// K2a (MFMA): per chunk, ckvT[dd][kd] = sum_c v[c][dd] k[c][kd] -> CKV8 int8.
// ---------------------------------------------------------------------------
__global__ __launch_bounds__(256)
void k_chunkA(const signed char* __restrict__ Kb8,
              const signed char* __restrict__ VbT8,
              signed char* __restrict__ CKV8)
{
    __shared__ __align__(16) short KTs[4096], VTs[4096];
    __shared__ __align__(16) signed char Cs8[4096];
    const int tid = threadIdx.x;
    const int bh = blockIdx.x >> 6, n = blockIdx.x & 63;
    const size_t kbase = ((size_t)bh * T_ + n * 64) * 64;          // [c][dd]
    const size_t vbase = (size_t)bh * T_ * 64 + (size_t)n * 4096;  // [dd][c]

    {
        const int off = tid * 16;
        int4 vr = *(const int4*)(VbT8 + vbase + off);
        const signed char* vb = (const signed char*)&vr;
        const int vrow = off >> 6, vcb = off & 63;
        #pragma unroll
        for (int jj = 0; jj < 2; ++jj) {
            s16x8 v;
            #pragma unroll
            for (int j = 0; j < 8; ++j)
                v[j] = (vb[jj*8+j] >= 0) ? BF_P1 : BF_M1;
            const int o = (vrow * 128 + (vcb + jj * 8) * 2) ^ ((vrow & 7) << 4);
            *(s16x8*)((char*)VTs + o) = v;
        }
        int4 kr = *(const int4*)(Kb8 + kbase + off);
        const signed char* kb = (const signed char*)&kr;
        const int c = off >> 6, d0 = off & 63;
        #pragma unroll
        for (int j = 0; j < 16; ++j) {
            const int dd = d0 + j;
            const short sv = (kb[j] >= 0) ? BF_P1 : BF_M1;
            const int o2 = (dd * 128 + c * 2) ^ ((dd & 7) << 4);
            *(short*)((char*)KTs + o2) = sv;
        }
    }
    __syncthreads();

    const int lane = tid & 63, w = tid >> 6;
    const int cl = lane & 15, rg = lane >> 4;
    auto frag = [&](const short* l, int rowbase, int kk) -> s16x8 {
        const int row = rowbase + cl;
        int off = row * 128 + kk * 64 + rg * 16;
        off ^= (row & 7) << 4;
        return *(const s16x8*)((const char*)l + off);
    };

    f32x4 a3[4];
    #pragma unroll
    for (int ni = 0; ni < 4; ++ni) a3[ni] = (f32x4)0.f;
    const s16x8 va0 = frag(VTs, w * 16, 0), va1 = frag(VTs, w * 16, 1);
    #pragma unroll
    for (int ni = 0; ni < 4; ++ni) {
        a3[ni] = MFMA16(va0, frag(KTs, ni * 16, 0), a3[ni]);
        a3[ni] = MFMA16(va1, frag(KTs, ni * 16, 1), a3[ni]);
    }
    #pragma unroll
    for (int ni = 0; ni < 4; ++ni)
        #pragma unroll
        for (int r = 0; r < 4; ++r) {
            const int m = w * 16 + rg * 4 + r;     // dd
            const int c = ni * 16 + cl;            // kd
            Cs8[m * 64 + c] = (signed char)(int)a3[ni][r];
        }
    __syncthreads();
    const size_t c8 = ((size_t)bh * 64 + n) * 4096;
    *(int4*)(CKV8 + c8 + tid * 16) = *(const int4*)(Cs8 + tid * 16);
}

// ---------------------------------------------------------------------------
// K3: integer exclusive scan of CKV8 over chunks -> PB bf16; FM fp32 exact.
// ---------------------------------------------------------------------------
__global__ __launch_bounds__(256)
void k_scan2(const signed char* __restrict__ CKV8, short* __restrict__ PB,
             float* __restrict__ FM, float* __restrict__ FC)
{
    const int bh = blockIdx.x >> 4;
    const int e  = (blockIdx.x & 15) * 256 + threadIdx.x;   // dd*64+kd
    const size_t b8 = (size_t)bh * N_ * 4096 + e;
    const size_t bp = (size_t)bh * N_ * 4096 + e;
    int run = 0;
    #pragma unroll
    for (int nn = 0; nn < 64; ++nn) {
        PB[bp + (size_t)nn * 4096] = (short)f2bf((float)run);
        run += (int)CKV8[b8 + (size_t)nn * 4096];
    }
    FM[(size_t)bh * 4096 + (e & 63) * 64 + (e >> 6)] = (float)run;
    if ((blockIdx.x & 15) == 0 && threadIdx.x == 0) FC[bh] = (float)T_;
}

// ---------------------------------------------------------------------------
// K4 (MFMA, fused): S = mask(Q K^T); intra = S V; cross = Q @ P;
// OMb = bf16((intra + cross) / total).
// ---------------------------------------------------------------------------
__global__ __launch_bounds__(256)
void k_cross3(const short* __restrict__ Qb, const signed char* __restrict__ Kb8,
              const signed char* __restrict__ VbT8, const short* __restrict__ PB,
              short* __restrict__ OMb)
{
    __shared__ __align__(16) short Qs[4096], Ks[4096], VTs[4096], Ps[4096], Ss[4096];
    const int tid = threadIdx.x;
    const int bh = blockIdx.x >> 6, n = blockIdx.x & 63;
    const size_t cbase = ((size_t)bh * T_ + n * 64) * 64;
    const size_t kbase = cbase;                                    // [c][dd]
    const size_t vbase = (size_t)bh * T_ * 64 + (size_t)n * 4096;  // [dd][c]

    auto stage_tile = [&](const short* g, short* l) {
        #pragma unroll
        for (int p = 0; p < 2; ++p) {
            const int off = tid * 16 + p * 4096;
            const int r = off >> 7;
            s16x8 v = *(const s16x8*)(g + (off >> 1));
            *(s16x8*)((char*)l + (off ^ ((r & 7) << 4))) = v;
        }
    };
    stage_tile(Qb + cbase, Qs);
    stage_tile(PB + ((size_t)bh * 64 + n) * 4096, Ps);
    {
        const int off = tid * 16;
        int4 kr = *(const int4*)(Kb8 + kbase + off);
        const signed char* kb = (const signed char*)&kr;
        int4 vr = *(const int4*)(VbT8 + vbase + off);
        const signed char* vb = (const signed char*)&vr;
        const int row = off >> 6, cb = off & 63;
        #pragma unroll
        for (int jj = 0; jj < 2; ++jj) {
            s16x8 kv, vv;
            #pragma unroll
            for (int j = 0; j < 8; ++j) {
                kv[j] = (kb[jj*8+j] >= 0) ? BF_P1 : BF_M1;
                vv[j] = (vb[jj*8+j] >= 0) ? BF_P1 : BF_M1;
            }
            const int o = (row * 128 + (cb + jj * 8) * 2) ^ ((row & 7) << 4);
            *(s16x8*)((char*)Ks  + o) = kv;
            *(s16x8*)((char*)VTs + o) = vv;
        }
    }
    __syncthreads();

    const int lane = tid & 63, w = tid >> 6;
    const int cl = lane & 15, rg = lane >> 4;
    auto frag = [&](const short* l, int rowbase, int kk) -> s16x8 {
        const int row = rowbase + cl;
        int off = row * 128 + kk * 64 + rg * 16;
        off ^= (row & 7) << 4;
        return *(const s16x8*)((const char*)l + off);
    };

    const s16x8 qa0 = frag(Qs, w * 16, 0), qa1 = frag(Qs, w * 16, 1);
    {
        f32x4 a1[4];
        #pragma unroll
        for (int ni = 0; ni < 4; ++ni) a1[ni] = (f32x4)0.f;
        #pragma unroll
        for (int ni = 0; ni < 4; ++ni) {
            a1[ni] = MFMA16(qa0, frag(Ks, ni * 16, 0), a1[ni]);
            a1[ni] = MFMA16(qa1, frag(Ks, ni * 16, 1), a1[ni]);
        }
        #pragma unroll
        for (int ni = 0; ni < 4; ++ni)
            #pragma unroll
            for (int r = 0; r < 4; ++r) {
                const int i = w * 16 + rg * 4 + r, j = ni * 16 + cl;
                const float v = (j <= i) ? a1[ni][r] : 0.f;
                const int off = (i * 128 + j * 2) ^ ((i & 7) << 4);
                *(short*)((char*)Ss + off) = (short)f2bf(v);
            }
    }
    __syncthreads();

    {
        f32x4 a2[4], a3[4];
        #pragma unroll
        for (int ni = 0; ni < 4; ++ni) { a2[ni] = (f32x4)0.f; a3[ni] = (f32x4)0.f; }
        const s16x8 sa0 = frag(Ss, w * 16, 0), sa1 = frag(Ss, w * 16, 1);
        #pragma unroll
        for (int ni = 0; ni < 4; ++ni) {
            a2[ni] = MFMA16(sa0, frag(VTs, ni * 16, 0), a2[ni]);
            a2[ni] = MFMA16(sa1, frag(VTs, ni * 16, 1), a2[ni]);
            a3[ni] = MFMA16(qa0, frag(Ps, ni * 16, 0), a3[ni]);
            a3[ni] = MFMA16(qa1, frag(Ps, ni * 16, 1), a3[ni]);
        }
        #pragma unroll
        for (int ni = 0; ni < 4; ++ni)
            #pragma unroll
            for (int r = 0; r < 4; ++r) {
                const int i = w * 16 + rg * 4 + r, j = ni * 16 + cl;
                const float invt = 1.0f / (float)(n * 64 + i + 1);
                const float f = (a2[ni][r] + a3[ni][r]) * invt;
                const int off = (i * 128 + j * 2) ^ ((i & 7) << 4);
                *(short*)((char*)Qs + off) = (short)f2bf(f);
            }
    }
    __syncthreads();

    const int bb = bh >> 4, h = bh & 15;
    #pragma unroll
    for (int p = 0; p < 2; ++p) {
        const int off = tid * 16 + p * 4096;
        const int r = off >> 7;
        const int lo = off ^ ((r & 7) << 4);
        s16x8 v = *(const s16x8*)((char*)Qs + lo);
        const size_t gi = ((size_t)bb * T_ + n * 64 + r) * D_
                        + h * 64 + ((off & 127) >> 1);
        *(s16x8*)(OMb + gi) = v;
    }
}

extern "C" void kernel_launch(void* const* d_in, const int* in_sizes, int n_in,
                              void* d_out, int out_size, void* d_ws, size_t ws_size,
                              hipStream_t stream)
{
    const float* X    = (const float*)d_in[0];
    const float* Wqkv = (const float*)d_in[1];
    const float* Wo   = (const float*)d_in[2];

    float* Y  = (float*)d_out;                       // [B,T,D]
    float* FM = Y + (size_t)B_ * T_ * D_;            // [B,H,64,64]
    float* FC = FM + (size_t)B_ * H_ * HD_ * HD_;    // [B,H,1,1]

    char* ws = (char*)d_ws;
    const size_t Mi = 1048576;
    short*       Qb    = (short*)(ws + 0 * Mi);     // 32 MiB
    short*       Xb    = (short*)(ws + 32 * Mi);    // 32 MiB (early)
    signed char* Kb8   = (signed char*)(ws + 32 * Mi);  // 16 MiB (late)
    signed char* VbT8  = (signed char*)(ws + 48 * Mi);  // 16 MiB (late)
    short*       PB    = (short*)(ws + 64 * Mi);    // 32 MiB
    short*       XS    = (short*)(ws + 128 * Mi);   // 64 MiB (early)
    short*       OMb   = (short*)(ws + 160 * Mi);   // 32 MiB (late, over XS hi)
    short*       WSq   = (short*)(ws + 192 * Mi);   //  8 MiB (early)
    signed char* CKV8  = (signed char*)(ws + 192 * Mi); // 16 MiB (late)
    short*       Wqb   = (short*)(ws + 208 * Mi);   //  2 MiB
    short*       WoS   = (short*)(ws + 210 * Mi);   //  2 MiB
    if (ws_size < (size_t)222 * Mi) return;

    dim3 blk(256), blkg(512);
    k_cvt_split<<<dim3(2048), blk, 0, stream>>>(X, XS, Xb, 4194304);
    k_cvt<<<dim3(512), blk, 0, stream>>>(Wqkv, Wqb, 262144);
    k_gemm<2, 1024, 4><<<dim3(256), blkg, 0, stream>>>(Xb, Wqb, Qb, nullptr, nullptr, nullptr);
    k_cvt_split<<<dim3(1024), blk, 0, stream>>>(Wqkv + (size_t)1024 * 1024, WSq, nullptr, 524288);
    k_gemm<0, 2048, 8><<<dim3(512), blkg, 0, stream>>>(XS, WSq, nullptr, Kb8, VbT8, nullptr);
    k_chunkA<<<dim3(4096), blk, 0, stream>>>(Kb8, VbT8, CKV8);
    k_scan2 <<<dim3(1024), blk, 0, stream>>>(CKV8, PB, FM, FC);
    k_cross3<<<dim3(4096), blk, 0, stream>>>(Qb, Kb8, VbT8, PB, OMb);
    k_cvt<<<dim3(512), blk, 0, stream>>>(Wo, WoS, 262144);
    k_gemm<1, 1024, 4><<<dim3(256), blkg, 0, stream>>>(OMb, WoS, nullptr, nullptr, nullptr, Y);
}

// Round 12
// 333.956 us; speedup vs baseline: 1.0176x; 1.0176x over previous
//
#include <hip/hip_runtime.h>
#include <cstdint>

// B=4, T=4096, D=1024, H=16, d=64, C=64, N=T/C=64
#define B_ 4
#define T_ 4096
#define D_ 1024
#define H_ 16
#define HD_ 64
#define N_ 64

typedef __attribute__((ext_vector_type(8))) short s16x8;
typedef __attribute__((ext_vector_type(4))) float f32x4;

__device__ __forceinline__ unsigned short f2bf(float f) {
    unsigned int u = __builtin_bit_cast(unsigned int, f);
    u += 0x7fffu + ((u >> 16) & 1u);          // RNE
    return (unsigned short)(u >> 16);
}
__device__ __forceinline__ float bf2f(unsigned short h) {
    unsigned int u = ((unsigned int)h) << 16;
    return __builtin_bit_cast(float, u);
}
__device__ __forceinline__ void gl2lds(const short* g, short* l) {
    __builtin_amdgcn_global_load_lds(
        (const __attribute__((address_space(1))) void*)g,
        (__attribute__((address_space(3))) void*)l, 16, 0, 0);
}
#define MFMA16(a, b, c) __builtin_amdgcn_mfma_f32_16x16x32_bf16(a, b, c, 0, 0, 0)
#define SB0() __builtin_amdgcn_sched_barrier(0)
#define BAR() __builtin_amdgcn_s_barrier()

#define BF_P1 ((short)0x3F80)
#define BF_M1 ((short)0xBF80)

// ---------------------------------------------------------------------------
// Converters.
// ---------------------------------------------------------------------------
__global__ __launch_bounds__(256)
void k_cvt_split(const float* __restrict__ in, short* __restrict__ out,
                 short* __restrict__ out_hi, int n4)
{
    int i = blockIdx.x * blockDim.x + threadIdx.x;
    const int stride = gridDim.x * blockDim.x;
    for (; i < n4; i += stride) {
        float4 f = ((const float4*)in)[i];
        const float v[4] = {f.x, f.y, f.z, f.w};
        s16x8 o;
        short4 hi4;
        #pragma unroll
        for (int j = 0; j < 4; ++j) {
            unsigned short h = f2bf(v[j]);
            o[j*2]   = (short)h;
            o[j*2+1] = (short)f2bf(v[j] - bf2f(h));
            ((short*)&hi4)[j] = (short)h;
        }
        ((s16x8*)out)[i] = o;
        if (out_hi) *(short4*)(out_hi + i * 4) = hi4;
    }
}
__global__ __launch_bounds__(256)
void k_cvt(const float* __restrict__ in, short* __restrict__ out, int n4)
{
    int i = blockIdx.x * blockDim.x + threadIdx.x;
    const int stride = gridDim.x * blockDim.x;
    for (; i < n4; i += stride) {
        float4 f = ((const float4*)in)[i];
        short4 o;
        o.x = (short)f2bf(f.x); o.y = (short)f2bf(f.y);
        o.z = (short)f2bf(f.z); o.w = (short)f2bf(f.w);
        *(short4*)(out + i * 4) = o;
    }
}

// ---------------------------------------------------------------------------
// bf16 MFMA GEMM, TLP structure: O = A @ B^T.
// 256x128 tile, BK=64, 512 thr (8 waves 4x2, per-wave 64x64 -> acc 64 VGPR),
// SINGLE-buffered 48 KiB LDS, __launch_bounds__(512,4) -> 2 blocks/CU.
// Loop: vmcnt(0) -> BAR -> {ds_reads + MFMAs, compiler-interleaved} -> BAR
// -> stage(t+1). The exposed vmcnt(0) drain at loop-top is covered by the
// co-resident block (cross-block TLP, m114/m97 mechanism). Swizzle: 128B
// rows, phys 16B slot = logical ^ (row&7), pre-swizzled gl2lds source
// (r5 layout, measured 0 conflicts).
// MODE 0: k/v epilogue (sign INT8 -> Kb8 [c][d] / VbT8 [d][c]).
// MODE 1: fp32 Y.  MODE 2: Q epilogue (bf16, *0.125).
// ---------------------------------------------------------------------------
template<int MODE, int KD, int NCB>
__global__ __launch_bounds__(512, 4)
void k_gemm2(const short* __restrict__ A, const short* __restrict__ Bm,
             short* __restrict__ Oq, signed char* __restrict__ K8,
             signed char* __restrict__ V8, float* __restrict__ Yf)
{
    __shared__ __align__(16) short LA[256 * 64];   // 32 KiB
    __shared__ __align__(16) short LB[128 * 64];   // 16 KiB

    const int tid = threadIdx.x;
    const int nwg = 64 * NCB;
    const int bid = blockIdx.x;
    const int sz  = (bid & 7) * (nwg >> 3) + (bid >> 3);   // XCD-contiguous
    const int cb  = sz % NCB, rb = sz / NCB;
    const int row0 = rb * 256, col0 = cb * 128;

    const int lane = tid & 63, w = tid >> 6;
    const int wr = w >> 1, wc = w & 1;
    const int cl = lane & 15, rg = lane >> 4;

    // staging: lane l -> row (l>>3), phys slot (l&7); src slot pre-swizzled.
    const int sr8 = lane >> 3;
    const int slg = ((lane & 7) ^ sr8) * 8;
    const short* gA = A  + (size_t)(row0 + w * 32 + sr8) * KD + slg;
    const short* gB = Bm + (size_t)(col0 + w * 16 + sr8) * KD + slg;

    f32x4 acc[4][4];
    #pragma unroll
    for (int i = 0; i < 4; ++i)
        #pragma unroll
        for (int j = 0; j < 4; ++j) acc[i][j] = (f32x4)0.f;

    auto stage = [&](int t) {
        const int ko = t * 64;
        #pragma unroll
        for (int c = 0; c < 4; ++c)
            gl2lds(gA + ko + (size_t)c * 8 * KD, &LA[(w * 32 + c * 8) * 64]);
        #pragma unroll
        for (int c = 0; c < 2; ++c)
            gl2lds(gB + ko + (size_t)c * 8 * KD, &LB[(w * 16 + c * 8) * 64]);
    };
    // swizzled fragment read: row R, logical 16B slot q (0..7)
    auto ldf = [&](const short* base, int R, int q) -> s16x8 {
        return *(const s16x8*)((const char*)base + R * 128 + ((q ^ (R & 7)) << 4));
    };

    const int nt = KD / 64;
    stage(0);
    for (int t = 0; t < nt; ++t) {
        asm volatile("s_waitcnt vmcnt(0)" ::: "memory");
        BAR();
        SB0();
        #pragma unroll
        for (int kk = 0; kk < 2; ++kk) {
            s16x8 fb[4];
            #pragma unroll
            for (int ni = 0; ni < 4; ++ni)
                fb[ni] = ldf(LB, wc * 64 + ni * 16 + cl, kk * 4 + rg);
            #pragma unroll
            for (int mi = 0; mi < 4; ++mi) {
                s16x8 fa = ldf(LA, wr * 64 + mi * 16 + cl, kk * 4 + rg);
                __builtin_amdgcn_s_setprio(1);
                #pragma unroll
                for (int ni = 0; ni < 4; ++ni)
                    acc[mi][ni] = MFMA16(fa, fb[ni], acc[mi][ni]);
                __builtin_amdgcn_s_setprio(0);
            }
        }
        SB0();
        BAR();
        if (t + 1 < nt) stage(t + 1);
    }

    const int m0 = row0 + wr * 64, n0 = col0 + wc * 64;
    if (MODE == 0) {
        const int s = 1 + (col0 >> 10);       // 1:k 2:v, uniform per block
        #pragma unroll
        for (int ni = 0; ni < 4; ++ni) {
            const int col = n0 + ni * 16 + cl;
            const int h = (col & 1023) >> 6, dd = col & 63;
            #pragma unroll
            for (int mi = 0; mi < 4; ++mi)
                #pragma unroll
                for (int r = 0; r < 4; ++r) {
                    const int bt = m0 + mi * 16 + rg * 4 + r;
                    const int bb = bt >> 12, t = bt & (T_ - 1);
                    const size_t bh64 = (size_t)(bb * H_ + h);
                    const signed char sg = (acc[mi][ni][r] >= 0.f) ? 1 : -1;
                    if (s == 1) {
                        K8[(bh64 * T_ + t) * 64 + dd] = sg;   // Kb8 [c][d]
                    } else {
                        const size_t otr = bh64 * ((size_t)T_ * 64)
                                         + (size_t)(t >> 6) * 4096 + dd * 64 + (t & 63);
                        V8[otr] = sg;                         // VbT8 [d][c]
                    }
                }
        }
    } else if (MODE == 2) {
        #pragma unroll
        for (int ni = 0; ni < 4; ++ni) {
            const int col = n0 + ni * 16 + cl;
            const int h = col >> 6, dd = col & 63;
            #pragma unroll
            for (int mi = 0; mi < 4; ++mi)
                #pragma unroll
                for (int r = 0; r < 4; ++r) {
                    const int bt = m0 + mi * 16 + rg * 4 + r;
                    const int bb = bt >> 12, t = bt & (T_ - 1);
                    Oq[((size_t)(bb * H_ + h) * T_ + t) * 64 + dd] =
                        (short)f2bf(acc[mi][ni][r] * 0.125f);
                }
        }
    } else {
        #pragma unroll
        for (int ni = 0; ni < 4; ++ni) {
            const int col = n0 + ni * 16 + cl;
            #pragma unroll
            for (int mi = 0; mi < 4; ++mi)
                #pragma unroll
                for (int r = 0; r < 4; ++r)
                    Yf[(size_t)(m0 + mi * 16 + rg * 4 + r) * D_ + col] =
                        acc[mi][ni][r];
        }
    }
}

// ---------------------------------------------------------------------------
// K2a (MFMA): per chunk, ckvT[dd][kd] = sum_c v[c][dd] k[c][kd] -> CKV8 int8.
// ---------------------------------------------------------------------------
__global__ __launch_bounds__(256)
void k_chunkA(const signed char* __restrict__ Kb8,
              const signed char* __restrict__ VbT8,
              signed char* __restrict__ CKV8)
{
    __shared__ __align__(16) short KTs[4096], VTs[4096];
    __shared__ __align__(16) signed char Cs8[4096];
    const int tid = threadIdx.x;
    const int bh = blockIdx.x >> 6, n = blockIdx.x & 63;
    const size_t kbase = ((size_t)bh * T_ + n * 64) * 64;          // [c][dd]
    const size_t vbase = (size_t)bh * T_ * 64 + (size_t)n * 4096;  // [dd][c]

    {
        const int off = tid * 16;
        int4 vr = *(const int4*)(VbT8 + vbase + off);
        const signed char* vb = (const signed char*)&vr;
        const int vrow = off >> 6, vcb = off & 63;
        #pragma unroll
        for (int jj = 0; jj < 2; ++jj) {
            s16x8 v;
            #pragma unroll
            for (int j = 0; j < 8; ++j)
                v[j] = (vb[jj*8+j] >= 0) ? BF_P1 : BF_M1;
            const int o = (vrow * 128 + (vcb + jj * 8) * 2) ^ ((vrow & 7) << 4);
            *(s16x8*)((char*)VTs + o) = v;
        }
        int4 kr = *(const int4*)(Kb8 + kbase + off);
        const signed char* kb = (const signed char*)&kr;
        const int c = off >> 6, d0 = off & 63;
        #pragma unroll
        for (int j = 0; j < 16; ++j) {
            const int dd = d0 + j;
            const short sv = (kb[j] >= 0) ? BF_P1 : BF_M1;
            const int o2 = (dd * 128 + c * 2) ^ ((dd & 7) << 4);
            *(short*)((char*)KTs + o2) = sv;
        }
    }
    __syncthreads();

    const int lane = tid & 63, w = tid >> 6;
    const int cl = lane & 15, rg = lane >> 4;
    auto frag = [&](const short* l, int rowbase, int kk) -> s16x8 {
        const int row = rowbase + cl;
        int off = row * 128 + kk * 64 + rg * 16;
        off ^= (row & 7) << 4;
        return *(const s16x8*)((const char*)l + off);
    };

    f32x4 a3[4];
    #pragma unroll
    for (int ni = 0; ni < 4; ++ni) a3[ni] = (f32x4)0.f;
    const s16x8 va0 = frag(VTs, w * 16, 0), va1 = frag(VTs, w * 16, 1);
    #pragma unroll
    for (int ni = 0; ni < 4; ++ni) {
        a3[ni] = MFMA16(va0, frag(KTs, ni * 16, 0), a3[ni]);
        a3[ni] = MFMA16(va1, frag(KTs, ni * 16, 1), a3[ni]);
    }
    #pragma unroll
    for (int ni = 0; ni < 4; ++ni)
        #pragma unroll
        for (int r = 0; r < 4; ++r) {
            const int m = w * 16 + rg * 4 + r;     // dd
            const int c = ni * 16 + cl;            // kd
            Cs8[m * 64 + c] = (signed char)(int)a3[ni][r];
        }
    __syncthreads();
    const size_t c8 = ((size_t)bh * 64 + n) * 4096;
    *(int4*)(CKV8 + c8 + tid * 16) = *(const int4*)(Cs8 + tid * 16);
}

// ---------------------------------------------------------------------------
// K3: integer exclusive scan of CKV8 over chunks -> PB bf16; FM fp32 exact.
// ---------------------------------------------------------------------------
__global__ __launch_bounds__(256)
void k_scan2(const signed char* __restrict__ CKV8, short* __restrict__ PB,
             float* __restrict__ FM, float* __restrict__ FC)
{
    const int bh = blockIdx.x >> 4;
    const int e  = (blockIdx.x & 15) * 256 + threadIdx.x;   // dd*64+kd
    const size_t b8 = (size_t)bh * N_ * 4096 + e;
    const size_t bp = (size_t)bh * N_ * 4096 + e;
    int run = 0;
    #pragma unroll
    for (int nn = 0; nn < 64; ++nn) {
        PB[bp + (size_t)nn * 4096] = (short)f2bf((float)run);
        run += (int)CKV8[b8 + (size_t)nn * 4096];
    }
    FM[(size_t)bh * 4096 + (e & 63) * 64 + (e >> 6)] = (float)run;
    if ((blockIdx.x & 15) == 0 && threadIdx.x == 0) FC[bh] = (float)T_;
}

// ---------------------------------------------------------------------------
// K4 (MFMA, fused): S = mask(Q K^T); intra = S V; cross = Q @ P;
// OMb = bf16((intra + cross) / total).
// ---------------------------------------------------------------------------
__global__ __launch_bounds__(256)
void k_cross3(const short* __restrict__ Qb, const signed char* __restrict__ Kb8,
              const signed char* __restrict__ VbT8, const short* __restrict__ PB,
              short* __restrict__ OMb)
{
    __shared__ __align__(16) short Qs[4096], Ks[4096], VTs[4096], Ps[4096], Ss[4096];
    const int tid = threadIdx.x;
    const int bh = blockIdx.x >> 6, n = blockIdx.x & 63;
    const size_t cbase = ((size_t)bh * T_ + n * 64) * 64;
    const size_t kbase = cbase;                                    // [c][dd]
    const size_t vbase = (size_t)bh * T_ * 64 + (size_t)n * 4096;  // [dd][c]

    auto stage_tile = [&](const short* g, short* l) {
        #pragma unroll
        for (int p = 0; p < 2; ++p) {
            const int off = tid * 16 + p * 4096;
            const int r = off >> 7;
            s16x8 v = *(const s16x8*)(g + (off >> 1));
            *(s16x8*)((char*)l + (off ^ ((r & 7) << 4))) = v;
        }
    };
    stage_tile(Qb + cbase, Qs);
    stage_tile(PB + ((size_t)bh * 64 + n) * 4096, Ps);
    {
        const int off = tid * 16;
        int4 kr = *(const int4*)(Kb8 + kbase + off);
        const signed char* kb = (const signed char*)&kr;
        int4 vr = *(const int4*)(VbT8 + vbase + off);
        const signed char* vb = (const signed char*)&vr;
        const int row = off >> 6, cb = off & 63;
        #pragma unroll
        for (int jj = 0; jj < 2; ++jj) {
            s16x8 kv, vv;
            #pragma unroll
            for (int j = 0; j < 8; ++j) {
                kv[j] = (kb[jj*8+j] >= 0) ? BF_P1 : BF_M1;
                vv[j] = (vb[jj*8+j] >= 0) ? BF_P1 : BF_M1;
            }
            const int o = (row * 128 + (cb + jj * 8) * 2) ^ ((row & 7) << 4);
            *(s16x8*)((char*)Ks  + o) = kv;
            *(s16x8*)((char*)VTs + o) = vv;
        }
    }
    __syncthreads();

    const int lane = tid & 63, w = tid >> 6;
    const int cl = lane & 15, rg = lane >> 4;
    auto frag = [&](const short* l, int rowbase, int kk) -> s16x8 {
        const int row = rowbase + cl;
        int off = row * 128 + kk * 64 + rg * 16;
        off ^= (row & 7) << 4;
        return *(const s16x8*)((const char*)l + off);
    };

    const s16x8 qa0 = frag(Qs, w * 16, 0), qa1 = frag(Qs, w * 16, 1);
    {
        f32x4 a1[4];
        #pragma unroll
        for (int ni = 0; ni < 4; ++ni) a1[ni] = (f32x4)0.f;
        #pragma unroll
        for (int ni = 0; ni < 4; ++ni) {
            a1[ni] = MFMA16(qa0, frag(Ks, ni * 16, 0), a1[ni]);
            a1[ni] = MFMA16(qa1, frag(Ks, ni * 16, 1), a1[ni]);
        }
        #pragma unroll
        for (int ni = 0; ni < 4; ++ni)
            #pragma unroll
            for (int r = 0; r < 4; ++r) {
                const int i = w * 16 + rg * 4 + r, j = ni * 16 + cl;
                const float v = (j <= i) ? a1[ni][r] : 0.f;
                const int off = (i * 128 + j * 2) ^ ((i & 7) << 4);
                *(short*)((char*)Ss + off) = (short)f2bf(v);
            }
    }
    __syncthreads();

    {
        f32x4 a2[4], a3[4];
        #pragma unroll
        for (int ni = 0; ni < 4; ++ni) { a2[ni] = (f32x4)0.f; a3[ni] = (f32x4)0.f; }
        const s16x8 sa0 = frag(Ss, w * 16, 0), sa1 = frag(Ss, w * 16, 1);
        #pragma unroll
        for (int ni = 0; ni < 4; ++ni) {
            a2[ni] = MFMA16(sa0, frag(VTs, ni * 16, 0), a2[ni]);
            a2[ni] = MFMA16(sa1, frag(VTs, ni * 16, 1), a2[ni]);
            a3[ni] = MFMA16(qa0, frag(Ps, ni * 16, 0), a3[ni]);
            a3[ni] = MFMA16(qa1, frag(Ps, ni * 16, 1), a3[ni]);
        }
        #pragma unroll
        for (int ni = 0; ni < 4; ++ni)
            #pragma unroll
            for (int r = 0; r < 4; ++r) {
                const int i = w * 16 + rg * 4 + r, j = ni * 16 + cl;
                const float invt = 1.0f / (float)(n * 64 + i + 1);
                const float f = (a2[ni][r] + a3[ni][r]) * invt;
                const int off = (i * 128 + j * 2) ^ ((i & 7) << 4);
                *(short*)((char*)Qs + off) = (short)f2bf(f);
            }
    }
    __syncthreads();

    const int bb = bh >> 4, h = bh & 15;
    #pragma unroll
    for (int p = 0; p < 2; ++p) {
        const int off = tid * 16 + p * 4096;
        const int r = off >> 7;
        const int lo = off ^ ((r & 7) << 4);
        s16x8 v = *(const s16x8*)((char*)Qs + lo);
        const size_t gi = ((size_t)bb * T_ + n * 64 + r) * D_
                        + h * 64 + ((off & 127) >> 1);
        *(s16x8*)(OMb + gi) = v;
    }
}

extern "C" void kernel_launch(void* const* d_in, const int* in_sizes, int n_in,
                              void* d_out, int out_size, void* d_ws, size_t ws_size,
                              hipStream_t stream)
{
    const float* X    = (const float*)d_in[0];
    const float* Wqkv = (const float*)d_in[1];
    const float* Wo   = (const float*)d_in[2];

    float* Y  = (float*)d_out;                       // [B,T,D]
    float* FM = Y + (size_t)B_ * T_ * D_;            // [B,H,64,64]
    float* FC = FM + (size_t)B_ * H_ * HD_ * HD_;    // [B,H,1,1]

    char* ws = (char*)d_ws;
    const size_t Mi = 1048576;
    short*       Qb    = (short*)(ws + 0 * Mi);     // 32 MiB
    short*       Xb    = (short*)(ws + 32 * Mi);    // 32 MiB (early)
    signed char* Kb8   = (signed char*)(ws + 32 * Mi);  // 16 MiB (late)
    signed char* VbT8  = (signed char*)(ws + 48 * Mi);  // 16 MiB (late)
    short*       PB    = (short*)(ws + 64 * Mi);    // 32 MiB
    short*       XS    = (short*)(ws + 128 * Mi);   // 64 MiB (early)
    short*       OMb   = (short*)(ws + 160 * Mi);   // 32 MiB (late, over XS hi)
    short*       WSq   = (short*)(ws + 192 * Mi);   //  8 MiB (early)
    signed char* CKV8  = (signed char*)(ws + 192 * Mi); // 16 MiB (late)
    short*       Wqb   = (short*)(ws + 208 * Mi);   //  2 MiB
    short*       WoS   = (short*)(ws + 210 * Mi);   //  2 MiB
    if (ws_size < (size_t)222 * Mi) return;

    dim3 blk(256), blkg(512);
    k_cvt_split<<<dim3(2048), blk, 0, stream>>>(X, XS, Xb, 4194304);
    k_cvt<<<dim3(512), blk, 0, stream>>>(Wqkv, Wqb, 262144);
    // Q GEMM: N=1024 -> NCB=8 -> grid 512 (2 blocks/CU)
    k_gemm2<2, 1024, 8><<<dim3(512), blkg, 0, stream>>>(Xb, Wqb, Qb, nullptr, nullptr, nullptr);
    k_cvt_split<<<dim3(1024), blk, 0, stream>>>(Wqkv + (size_t)1024 * 1024, WSq, nullptr, 524288);
    // K/V GEMM: N=2048 -> NCB=16 -> grid 1024 (2 rounds, 2 blocks/CU)
    k_gemm2<0, 2048, 16><<<dim3(1024), blkg, 0, stream>>>(XS, WSq, nullptr, Kb8, VbT8, nullptr);
    k_chunkA<<<dim3(4096), blk, 0, stream>>>(Kb8, VbT8, CKV8);
    k_scan2 <<<dim3(1024), blk, 0, stream>>>(CKV8, PB, FM, FC);
    k_cross3<<<dim3(4096), blk, 0, stream>>>(Qb, Kb8, VbT8, PB, OMb);
    k_cvt<<<dim3(512), blk, 0, stream>>>(Wo, WoS, 262144);
    // out GEMM: N=1024 -> NCB=8 -> grid 512
    k_gemm2<1, 1024, 8><<<dim3(512), blkg, 0, stream>>>(OMb, WoS, nullptr, nullptr, nullptr, Y);
}

// Round 13
// 262.596 us; speedup vs baseline: 1.2941x; 1.2718x over previous
//
#include <hip/hip_runtime.h>
#include <cstdint>

// B=4, T=4096, D=1024, H=16, d=64, C=64, N=T/C=64
#define B_ 4
#define T_ 4096
#define D_ 1024
#define H_ 16
#define HD_ 64
#define N_ 64

typedef __attribute__((ext_vector_type(8))) short s16x8;
typedef __attribute__((ext_vector_type(4))) float f32x4;

__device__ __forceinline__ unsigned short f2bf(float f) {
    unsigned int u = __builtin_bit_cast(unsigned int, f);
    u += 0x7fffu + ((u >> 16) & 1u);          // RNE
    return (unsigned short)(u >> 16);
}
__device__ __forceinline__ float bf2f(unsigned short h) {
    unsigned int u = ((unsigned int)h) << 16;
    return __builtin_bit_cast(float, u);
}
__device__ __forceinline__ void gl2lds(const short* g, short* l) {
    __builtin_amdgcn_global_load_lds(
        (const __attribute__((address_space(1))) void*)g,
        (__attribute__((address_space(3))) void*)l, 16, 0, 0);
}
#define MFMA16(a, b, c) __builtin_amdgcn_mfma_f32_16x16x32_bf16(a, b, c, 0, 0, 0)
#define SB0() __builtin_amdgcn_sched_barrier(0)
#define BAR() __builtin_amdgcn_s_barrier()

#define BF_P1 ((short)0x3F80)
#define BF_M1 ((short)0xBF80)

// ---------------------------------------------------------------------------
// Converter: fp32 -> plain bf16. (hi/lo split deleted: the interleaved-dot
// "split" computed sum(ah*bh)+sum(al*bl) — the cross terms were never there,
// so it was numerically == plain bf16. Plain bf16 K=1024 keeps the same
// retained sum and halves GEMM FLOPs + LDS traffic.)
// ---------------------------------------------------------------------------
__global__ __launch_bounds__(256)
void k_cvt(const float* __restrict__ in, short* __restrict__ out, int n4)
{
    int i = blockIdx.x * blockDim.x + threadIdx.x;
    const int stride = gridDim.x * blockDim.x;
    for (; i < n4; i += stride) {
        float4 f = ((const float4*)in)[i];
        short4 o;
        o.x = (short)f2bf(f.x); o.y = (short)f2bf(f.y);
        o.z = (short)f2bf(f.z); o.w = (short)f2bf(f.w);
        *(short4*)(out + i * 4) = o;
    }
}

// ---------------------------------------------------------------------------
// bf16 MFMA GEMM, TLP structure (r12 core, frozen): O = A @ B^T.
// 256x128 tile, BK=64, 512 thr (8 waves 4x2, per-wave 64x64, acc 64 VGPR),
// single-buffered 48 KiB LDS, __launch_bounds__(512,4) -> 2 blocks/CU.
// Swizzle: 128B rows, phys 16B slot = logical ^ (row&7), pre-swizzled src.
// MODE 0: fused qkv epilogue by col0>>10: s=0 -> Qb bf16*0.125,
//         s=1 -> Kb8 int8 sign [c][d], s=2 -> VbT8 int8 sign [d][c].
// MODE 1: fp32 Y.
// ---------------------------------------------------------------------------
template<int MODE, int KD, int NCB>
__global__ __launch_bounds__(512, 4)
void k_gemm2(const short* __restrict__ A, const short* __restrict__ Bm,
             short* __restrict__ Oq, signed char* __restrict__ K8,
             signed char* __restrict__ V8, float* __restrict__ Yf)
{
    __shared__ __align__(16) short LA[256 * 64];   // 32 KiB
    __shared__ __align__(16) short LB[128 * 64];   // 16 KiB

    const int tid = threadIdx.x;
    const int nwg = 64 * NCB;
    const int bid = blockIdx.x;
    const int sz  = (bid & 7) * (nwg >> 3) + (bid >> 3);   // XCD-contiguous
    const int cb  = sz % NCB, rb = sz / NCB;
    const int row0 = rb * 256, col0 = cb * 128;

    const int lane = tid & 63, w = tid >> 6;
    const int wr = w >> 1, wc = w & 1;
    const int cl = lane & 15, rg = lane >> 4;

    const int sr8 = lane >> 3;
    const int slg = ((lane & 7) ^ sr8) * 8;
    const short* gA = A  + (size_t)(row0 + w * 32 + sr8) * KD + slg;
    const short* gB = Bm + (size_t)(col0 + w * 16 + sr8) * KD + slg;

    f32x4 acc[4][4];
    #pragma unroll
    for (int i = 0; i < 4; ++i)
        #pragma unroll
        for (int j = 0; j < 4; ++j) acc[i][j] = (f32x4)0.f;

    auto stage = [&](int t) {
        const int ko = t * 64;
        #pragma unroll
        for (int c = 0; c < 4; ++c)
            gl2lds(gA + ko + (size_t)c * 8 * KD, &LA[(w * 32 + c * 8) * 64]);
        #pragma unroll
        for (int c = 0; c < 2; ++c)
            gl2lds(gB + ko + (size_t)c * 8 * KD, &LB[(w * 16 + c * 8) * 64]);
    };
    auto ldf = [&](const short* base, int R, int q) -> s16x8 {
        return *(const s16x8*)((const char*)base + R * 128 + ((q ^ (R & 7)) << 4));
    };

    const int nt = KD / 64;
    stage(0);
    for (int t = 0; t < nt; ++t) {
        asm volatile("s_waitcnt vmcnt(0)" ::: "memory");
        BAR();
        SB0();
        #pragma unroll
        for (int kk = 0; kk < 2; ++kk) {
            s16x8 fb[4];
            #pragma unroll
            for (int ni = 0; ni < 4; ++ni)
                fb[ni] = ldf(LB, wc * 64 + ni * 16 + cl, kk * 4 + rg);
            #pragma unroll
            for (int mi = 0; mi < 4; ++mi) {
                s16x8 fa = ldf(LA, wr * 64 + mi * 16 + cl, kk * 4 + rg);
                __builtin_amdgcn_s_setprio(1);
                #pragma unroll
                for (int ni = 0; ni < 4; ++ni)
                    acc[mi][ni] = MFMA16(fa, fb[ni], acc[mi][ni]);
                __builtin_amdgcn_s_setprio(0);
            }
        }
        SB0();
        BAR();
        if (t + 1 < nt) stage(t + 1);
    }

    const int m0 = row0 + wr * 64, n0 = col0 + wc * 64;
    if (MODE == 0) {
        const int s = col0 >> 10;             // 0:q 1:k 2:v, uniform per block
        #pragma unroll
        for (int ni = 0; ni < 4; ++ni) {
            const int col = n0 + ni * 16 + cl;
            const int h = (col & 1023) >> 6, dd = col & 63;
            #pragma unroll
            for (int mi = 0; mi < 4; ++mi)
                #pragma unroll
                for (int r = 0; r < 4; ++r) {
                    const int bt = m0 + mi * 16 + rg * 4 + r;
                    const int bb = bt >> 12, t = bt & (T_ - 1);
                    const size_t bh64 = (size_t)(bb * H_ + h);
                    const float v = acc[mi][ni][r];
                    if (s == 0) {
                        Oq[(bh64 * T_ + t) * 64 + dd] =
                            (short)f2bf(v * 0.125f);          // Qb [c][d]
                    } else if (s == 1) {
                        K8[(bh64 * T_ + t) * 64 + dd] =
                            (v >= 0.f) ? 1 : -1;              // Kb8 [c][d]
                    } else {
                        const size_t otr = bh64 * ((size_t)T_ * 64)
                                         + (size_t)(t >> 6) * 4096 + dd * 64 + (t & 63);
                        V8[otr] = (v >= 0.f) ? 1 : -1;        // VbT8 [d][c]
                    }
                }
        }
    } else {
        #pragma unroll
        for (int ni = 0; ni < 4; ++ni) {
            const int col = n0 + ni * 16 + cl;
            #pragma unroll
            for (int mi = 0; mi < 4; ++mi)
                #pragma unroll
                for (int r = 0; r < 4; ++r)
                    Yf[(size_t)(m0 + mi * 16 + rg * 4 + r) * D_ + col] =
                        acc[mi][ni][r];
        }
    }
}

// ---------------------------------------------------------------------------
// K2a (MFMA): per chunk, ckvT[dd][kd] = sum_c v[c][dd] k[c][kd] -> CKV8 int8.
// ---------------------------------------------------------------------------
__global__ __launch_bounds__(256)
void k_chunkA(const signed char* __restrict__ Kb8,
              const signed char* __restrict__ VbT8,
              signed char* __restrict__ CKV8)
{
    __shared__ __align__(16) short KTs[4096], VTs[4096];
    __shared__ __align__(16) signed char Cs8[4096];
    const int tid = threadIdx.x;
    const int bh = blockIdx.x >> 6, n = blockIdx.x & 63;
    const size_t kbase = ((size_t)bh * T_ + n * 64) * 64;          // [c][dd]
    const size_t vbase = (size_t)bh * T_ * 64 + (size_t)n * 4096;  // [dd][c]

    {
        const int off = tid * 16;
        int4 vr = *(const int4*)(VbT8 + vbase + off);
        const signed char* vb = (const signed char*)&vr;
        const int vrow = off >> 6, vcb = off & 63;
        #pragma unroll
        for (int jj = 0; jj < 2; ++jj) {
            s16x8 v;
            #pragma unroll
            for (int j = 0; j < 8; ++j)
                v[j] = (vb[jj*8+j] >= 0) ? BF_P1 : BF_M1;
            const int o = (vrow * 128 + (vcb + jj * 8) * 2) ^ ((vrow & 7) << 4);
            *(s16x8*)((char*)VTs + o) = v;
        }
        int4 kr = *(const int4*)(Kb8 + kbase + off);
        const signed char* kb = (const signed char*)&kr;
        const int c = off >> 6, d0 = off & 63;
        #pragma unroll
        for (int j = 0; j < 16; ++j) {
            const int dd = d0 + j;
            const short sv = (kb[j] >= 0) ? BF_P1 : BF_M1;
            const int o2 = (dd * 128 + c * 2) ^ ((dd & 7) << 4);
            *(short*)((char*)KTs + o2) = sv;
        }
    }
    __syncthreads();

    const int lane = tid & 63, w = tid >> 6;
    const int cl = lane & 15, rg = lane >> 4;
    auto frag = [&](const short* l, int rowbase, int kk) -> s16x8 {
        const int row = rowbase + cl;
        int off = row * 128 + kk * 64 + rg * 16;
        off ^= (row & 7) << 4;
        return *(const s16x8*)((const char*)l + off);
    };

    f32x4 a3[4];
    #pragma unroll
    for (int ni = 0; ni < 4; ++ni) a3[ni] = (f32x4)0.f;
    const s16x8 va0 = frag(VTs, w * 16, 0), va1 = frag(VTs, w * 16, 1);
    #pragma unroll
    for (int ni = 0; ni < 4; ++ni) {
        a3[ni] = MFMA16(va0, frag(KTs, ni * 16, 0), a3[ni]);
        a3[ni] = MFMA16(va1, frag(KTs, ni * 16, 1), a3[ni]);
    }
    #pragma unroll
    for (int ni = 0; ni < 4; ++ni)
        #pragma unroll
        for (int r = 0; r < 4; ++r) {
            const int m = w * 16 + rg * 4 + r;     // dd
            const int c = ni * 16 + cl;            // kd
            Cs8[m * 64 + c] = (signed char)(int)a3[ni][r];
        }
    __syncthreads();
    const size_t c8 = ((size_t)bh * 64 + n) * 4096;
    *(int4*)(CKV8 + c8 + tid * 16) = *(const int4*)(Cs8 + tid * 16);
}

// ---------------------------------------------------------------------------
// K3: integer exclusive scan of CKV8 over chunks -> PB bf16; FM fp32 exact.
// ---------------------------------------------------------------------------
__global__ __launch_bounds__(256)
void k_scan2(const signed char* __restrict__ CKV8, short* __restrict__ PB,
             float* __restrict__ FM, float* __restrict__ FC)
{
    const int bh = blockIdx.x >> 4;
    const int e  = (blockIdx.x & 15) * 256 + threadIdx.x;   // dd*64+kd
    const size_t b8 = (size_t)bh * N_ * 4096 + e;
    const size_t bp = (size_t)bh * N_ * 4096 + e;
    int run = 0;
    #pragma unroll
    for (int nn = 0; nn < 64; ++nn) {
        PB[bp + (size_t)nn * 4096] = (short)f2bf((float)run);
        run += (int)CKV8[b8 + (size_t)nn * 4096];
    }
    FM[(size_t)bh * 4096 + (e & 63) * 64 + (e >> 6)] = (float)run;
    if ((blockIdx.x & 15) == 0 && threadIdx.x == 0) FC[bh] = (float)T_;
}

// ---------------------------------------------------------------------------
// K4 (MFMA, fused): S = mask(Q K^T); intra = S V; cross = Q @ P;
// OMb = bf16((intra + cross) / total).
// ---------------------------------------------------------------------------
__global__ __launch_bounds__(256)
void k_cross3(const short* __restrict__ Qb, const signed char* __restrict__ Kb8,
              const signed char* __restrict__ VbT8, const short* __restrict__ PB,
              short* __restrict__ OMb)
{
    __shared__ __align__(16) short Qs[4096], Ks[4096], VTs[4096], Ps[4096], Ss[4096];
    const int tid = threadIdx.x;
    const int bh = blockIdx.x >> 6, n = blockIdx.x & 63;
    const size_t cbase = ((size_t)bh * T_ + n * 64) * 64;
    const size_t kbase = cbase;                                    // [c][dd]
    const size_t vbase = (size_t)bh * T_ * 64 + (size_t)n * 4096;  // [dd][c]

    auto stage_tile = [&](const short* g, short* l) {
        #pragma unroll
        for (int p = 0; p < 2; ++p) {
            const int off = tid * 16 + p * 4096;
            const int r = off >> 7;
            s16x8 v = *(const s16x8*)(g + (off >> 1));
            *(s16x8*)((char*)l + (off ^ ((r & 7) << 4))) = v;
        }
    };
    stage_tile(Qb + cbase, Qs);
    stage_tile(PB + ((size_t)bh * 64 + n) * 4096, Ps);
    {
        const int off = tid * 16;
        int4 kr = *(const int4*)(Kb8 + kbase + off);
        const signed char* kb = (const signed char*)&kr;
        int4 vr = *(const int4*)(VbT8 + vbase + off);
        const signed char* vb = (const signed char*)&vr;
        const int row = off >> 6, cb = off & 63;
        #pragma unroll
        for (int jj = 0; jj < 2; ++jj) {
            s16x8 kv, vv;
            #pragma unroll
            for (int j = 0; j < 8; ++j) {
                kv[j] = (kb[jj*8+j] >= 0) ? BF_P1 : BF_M1;
                vv[j] = (vb[jj*8+j] >= 0) ? BF_P1 : BF_M1;
            }
            const int o = (row * 128 + (cb + jj * 8) * 2) ^ ((row & 7) << 4);
            *(s16x8*)((char*)Ks  + o) = kv;
            *(s16x8*)((char*)VTs + o) = vv;
        }
    }
    __syncthreads();

    const int lane = tid & 63, w = tid >> 6;
    const int cl = lane & 15, rg = lane >> 4;
    auto frag = [&](const short* l, int rowbase, int kk) -> s16x8 {
        const int row = rowbase + cl;
        int off = row * 128 + kk * 64 + rg * 16;
        off ^= (row & 7) << 4;
        return *(const s16x8*)((const char*)l + off);
    };

    const s16x8 qa0 = frag(Qs, w * 16, 0), qa1 = frag(Qs, w * 16, 1);
    {
        f32x4 a1[4];
        #pragma unroll
        for (int ni = 0; ni < 4; ++ni) a1[ni] = (f32x4)0.f;
        #pragma unroll
        for (int ni = 0; ni < 4; ++ni) {
            a1[ni] = MFMA16(qa0, frag(Ks, ni * 16, 0), a1[ni]);
            a1[ni] = MFMA16(qa1, frag(Ks, ni * 16, 1), a1[ni]);
        }
        #pragma unroll
        for (int ni = 0; ni < 4; ++ni)
            #pragma unroll
            for (int r = 0; r < 4; ++r) {
                const int i = w * 16 + rg * 4 + r, j = ni * 16 + cl;
                const float v = (j <= i) ? a1[ni][r] : 0.f;
                const int off = (i * 128 + j * 2) ^ ((i & 7) << 4);
                *(short*)((char*)Ss + off) = (short)f2bf(v);
            }
    }
    __syncthreads();

    {
        f32x4 a2[4], a3[4];
        #pragma unroll
        for (int ni = 0; ni < 4; ++ni) { a2[ni] = (f32x4)0.f; a3[ni] = (f32x4)0.f; }
        const s16x8 sa0 = frag(Ss, w * 16, 0), sa1 = frag(Ss, w * 16, 1);
        #pragma unroll
        for (int ni = 0; ni < 4; ++ni) {
            a2[ni] = MFMA16(sa0, frag(VTs, ni * 16, 0), a2[ni]);
            a2[ni] = MFMA16(sa1, frag(VTs, ni * 16, 1), a2[ni]);
            a3[ni] = MFMA16(qa0, frag(Ps, ni * 16, 0), a3[ni]);
            a3[ni] = MFMA16(qa1, frag(Ps, ni * 16, 1), a3[ni]);
        }
        #pragma unroll
        for (int ni = 0; ni < 4; ++ni)
            #pragma unroll
            for (int r = 0; r < 4; ++r) {
                const int i = w * 16 + rg * 4 + r, j = ni * 16 + cl;
                const float invt = 1.0f / (float)(n * 64 + i + 1);
                const float f = (a2[ni][r] + a3[ni][r]) * invt;
                const int off = (i * 128 + j * 2) ^ ((i & 7) << 4);
                *(short*)((char*)Qs + off) = (short)f2bf(f);
            }
    }
    __syncthreads();

    const int bb = bh >> 4, h = bh & 15;
    #pragma unroll
    for (int p = 0; p < 2; ++p) {
        const int off = tid * 16 + p * 4096;
        const int r = off >> 7;
        const int lo = off ^ ((r & 7) << 4);
        s16x8 v = *(const s16x8*)((char*)Qs + lo);
        const size_t gi = ((size_t)bb * T_ + n * 64 + r) * D_
                        + h * 64 + ((off & 127) >> 1);
        *(s16x8*)(OMb + gi) = v;
    }
}

extern "C" void kernel_launch(void* const* d_in, const int* in_sizes, int n_in,
                              void* d_out, int out_size, void* d_ws, size_t ws_size,
                              hipStream_t stream)
{
    const float* X    = (const float*)d_in[0];
    const float* Wqkv = (const float*)d_in[1];
    const float* Wo   = (const float*)d_in[2];

    float* Y  = (float*)d_out;                       // [B,T,D]
    float* FM = Y + (size_t)B_ * T_ * D_;            // [B,H,64,64]
    float* FC = FM + (size_t)B_ * H_ * HD_ * HD_;    // [B,H,1,1]

    char* ws = (char*)d_ws;
    const size_t Mi = 1048576;
    // Timeline: cvt X->Xb@96, cvt Wqkv->Wqkvb@144; fused qkv GEMM
    // (Xb,Wqkvb -> Qb@0, Kb8@32, VbT8@48); chunkA -> CKV8@128;
    // scan2 -> PB@64, FM, FC; cross3 -> OMb@96 (over dead Xb);
    // cvt Wo->WoS@150; out GEMM (OMb,WoS -> Y).
    short*       Qb     = (short*)(ws + 0 * Mi);         // 32 MiB
    signed char* Kb8    = (signed char*)(ws + 32 * Mi);  // 16 MiB
    signed char* VbT8   = (signed char*)(ws + 48 * Mi);  // 16 MiB
    short*       PB     = (short*)(ws + 64 * Mi);        // 32 MiB
    short*       Xb     = (short*)(ws + 96 * Mi);        // 32 MiB (early)
    short*       OMb    = (short*)(ws + 96 * Mi);        // 32 MiB (late)
    signed char* CKV8   = (signed char*)(ws + 128 * Mi); // 16 MiB
    short*       Wqkvb  = (short*)(ws + 144 * Mi);       //  6 MiB
    short*       WoS    = (short*)(ws + 150 * Mi);       //  2 MiB
    if (ws_size < (size_t)152 * Mi) return;

    dim3 blk(256), blkg(512);
    k_cvt<<<dim3(2048), blk, 0, stream>>>(X, Xb, 4194304);
    k_cvt<<<dim3(1024), blk, 0, stream>>>(Wqkv, Wqkvb, 786432);
    // fused QKV GEMM: M=16384, N=3072, K=1024 -> NCB=24, grid 1536
    k_gemm2<0, 1024, 24><<<dim3(1536), blkg, 0, stream>>>(Xb, Wqkvb, Qb, Kb8, VbT8, nullptr);
    k_chunkA<<<dim3(4096), blk, 0, stream>>>(Kb8, VbT8, CKV8);
    k_scan2 <<<dim3(1024), blk, 0, stream>>>(CKV8, PB, FM, FC);
    k_cross3<<<dim3(4096), blk, 0, stream>>>(Qb, Kb8, VbT8, PB, OMb);
    k_cvt<<<dim3(512), blk, 0, stream>>>(Wo, WoS, 262144);
    // out GEMM: M=16384, N=1024, K=1024 -> NCB=8, grid 512
    k_gemm2<1, 1024, 8><<<dim3(512), blkg, 0, stream>>>(OMb, WoS, nullptr, nullptr, nullptr, Y);
}